// Round 1
// baseline (791.401 us; speedup 1.0000x reference)
//
#include <hip/hip_runtime.h>
#include <math.h>

#define B_  16
#define C_  256
#define N_  2048
#define CQ_ 64

// ---------------- Kernel 1: fused projections f = relu(Wf x + bf), g, h ----
// Grid: (N/64, 6, B). Tile [64 o][64 n], K = 256 in 4 steps of 64.
__global__ __launch_bounds__(256) void proj_kernel(
    const float* __restrict__ x,
    const float* __restrict__ Wf, const float* __restrict__ bf,
    const float* __restrict__ Wg, const float* __restrict__ bg,
    const float* __restrict__ Wh, const float* __restrict__ bh,
    float* __restrict__ fo, float* __restrict__ go, float* __restrict__ ho)
{
    const int b  = blockIdx.z;
    const int og = blockIdx.y;
    const int nbase = blockIdx.x * 64;
    const float* W; const float* bias; float* y; int orow; int OC;
    if (og == 0)      { W = Wf; bias = bf; y = fo; orow = 0;         OC = CQ_; }
    else if (og == 1) { W = Wg; bias = bg; y = go; orow = 0;         OC = CQ_; }
    else              { W = Wh; bias = bh; y = ho; orow = (og-2)*64; OC = C_;  }

    __shared__ float Wt[64][68];   // [k][o], pad 68 breaks column-read conflicts
    __shared__ float Xt[64][68];   // [k][n]

    const int t  = threadIdx.x;
    const int to = (t >> 4) * 4;
    const int tn = (t & 15) * 4;

    float acc[4][4] = {};

    for (int k0 = 0; k0 < C_; k0 += 64) {
        __syncthreads();
        #pragma unroll
        for (int p = 0; p < 4; ++p) {
            const int r  = (t >> 4) + p * 16;
            const int cc = (t & 15) * 4;
            float4 w4 = *(const float4*)&W[(size_t)(orow + r) * C_ + k0 + cc];
            Wt[cc+0][r] = w4.x; Wt[cc+1][r] = w4.y; Wt[cc+2][r] = w4.z; Wt[cc+3][r] = w4.w;
            float4 x4 = *(const float4*)&x[((size_t)b * C_ + k0 + r) * N_ + nbase + cc];
            *(float4*)&Xt[r][cc] = x4;
        }
        __syncthreads();
        #pragma unroll 16
        for (int kk = 0; kk < 64; ++kk) {
            float4 wv = *(const float4*)&Wt[kk][to];
            float4 xv = *(const float4*)&Xt[kk][tn];
            const float* wp = (const float*)&wv;
            const float* xp = (const float*)&xv;
            #pragma unroll
            for (int i = 0; i < 4; ++i)
                #pragma unroll
                for (int j = 0; j < 4; ++j)
                    acc[i][j] = fmaf(wp[i], xp[j], acc[i][j]);
        }
    }

    #pragma unroll
    for (int i = 0; i < 4; ++i) {
        const float bi = bias[orow + to + i];
        float4 v;
        v.x = fmaxf(acc[i][0] + bi, 0.0f);
        v.y = fmaxf(acc[i][1] + bi, 0.0f);
        v.z = fmaxf(acc[i][2] + bi, 0.0f);
        v.w = fmaxf(acc[i][3] + bi, 0.0f);
        *(float4*)&y[((size_t)b * OC + orow + to + i) * N_ + nbase + tn] = v;
    }
}

// ---------------- Kernel 2: per-(b,n) row stats of s = g^T f -----------------
// M[b,n] = max_m s ; Z[b,n] = sum_m exp(s - M). Grid: (N/64, B), block 256.
__global__ __launch_bounds__(256) void stats_kernel(
    const float* __restrict__ fo, const float* __restrict__ go,
    float* __restrict__ Mw, float* __restrict__ Zw)
{
    const int b = blockIdx.y;
    const int nbase = blockIdx.x * 64;

    __shared__ float Gt[64][65];   // [c][n]
    __shared__ float Ft[64][68];   // [c][m]
    __shared__ float pmax[64][17];
    __shared__ float psum[64][17];

    const int t  = threadIdx.x;
    const int nn = t & 63;
    const int cb = t >> 6;

    #pragma unroll
    for (int p = 0; p < 16; ++p)
        Gt[cb + p*4][nn] = go[((size_t)b * CQ_ + cb + p*4) * N_ + nbase + nn];

    const int sn = (t & 15) * 4;
    const int sm = (t >> 4) * 4;

    float tmax[4] = {-1e30f, -1e30f, -1e30f, -1e30f};
    float tsum[4] = {0.f, 0.f, 0.f, 0.f};

    for (int m0 = 0; m0 < N_; m0 += 64) {
        __syncthreads();
        #pragma unroll
        for (int p = 0; p < 16; ++p)
            Ft[cb + p*4][nn] = fo[((size_t)b * CQ_ + cb + p*4) * N_ + m0 + nn];
        __syncthreads();

        float s[4][4] = {};
        #pragma unroll 8
        for (int c = 0; c < 64; ++c) {
            const float g0 = Gt[c][sn+0], g1 = Gt[c][sn+1];
            const float g2 = Gt[c][sn+2], g3 = Gt[c][sn+3];
            float4 fv = *(const float4*)&Ft[c][sm];
            const float* fp = (const float*)&fv;
            #pragma unroll
            for (int j = 0; j < 4; ++j) {
                s[0][j] = fmaf(g0, fp[j], s[0][j]);
                s[1][j] = fmaf(g1, fp[j], s[1][j]);
                s[2][j] = fmaf(g2, fp[j], s[2][j]);
                s[3][j] = fmaf(g3, fp[j], s[3][j]);
            }
        }
        #pragma unroll
        for (int i = 0; i < 4; ++i) {
            const float lm = fmaxf(fmaxf(s[i][0], s[i][1]), fmaxf(s[i][2], s[i][3]));
            const float nm = fmaxf(tmax[i], lm);
            tsum[i] = tsum[i] * __expf(tmax[i] - nm)
                    + __expf(s[i][0]-nm) + __expf(s[i][1]-nm)
                    + __expf(s[i][2]-nm) + __expf(s[i][3]-nm);
            tmax[i] = nm;
        }
    }

    __syncthreads();
    #pragma unroll
    for (int i = 0; i < 4; ++i) {
        pmax[sn + i][t >> 4] = tmax[i];
        psum[sn + i][t >> 4] = tsum[i];
    }
    __syncthreads();
    if (t < 64) {
        float m = -1e30f;
        #pragma unroll
        for (int k = 0; k < 16; ++k) m = fmaxf(m, pmax[t][k]);
        float ss = 0.f;
        #pragma unroll
        for (int k = 0; k < 16; ++k) ss += psum[t][k] * __expf(pmax[t][k] - m);
        Mw[(size_t)b * N_ + nbase + t] = m;
        Zw[(size_t)b * N_ + nbase + t] = ss;
    }
}

// ---------------- Kernel 3: o = h @ beta (recompute s), out = gamma*o + x ---
// Grid: (N/64, B); block tile: all 256 c x 64 m, loop n in tiles of 32.
__global__ __launch_bounds__(256) void out_kernel(
    const float* __restrict__ x,
    const float* __restrict__ fo, const float* __restrict__ go,
    const float* __restrict__ ho,
    const float* __restrict__ Mw, const float* __restrict__ Zw,
    const float* __restrict__ gamma_p,
    float* __restrict__ out)
{
    const int b = blockIdx.y;
    const int mbase = blockIdx.x * 64;

    __shared__ float Ft[64][68];    // f: [c][m]  (64 x 64)
    __shared__ float Gt[64][33];    // g: [c][n]  (64 x 32)
    __shared__ float Ht[256][33];   // h: [c][n]  (256 x 32)
    __shared__ float Pt[32][68];    // beta tile: [n][m]
    __shared__ float Mn[32];
    __shared__ float rZn[32];

    const int t = threadIdx.x;
    const float gamma = gamma_p[0];

    // stage Ft once (f at this block's m-tile)
    {
        const int mm4 = (t & 15) * 4;
        #pragma unroll
        for (int p = 0; p < 4; ++p) {
            const int c = (t >> 4) + p * 16;
            float4 v = *(const float4*)&fo[((size_t)b * CQ_ + c) * N_ + mbase + mm4];
            Ft[c][mm4+0] = v.x; Ft[c][mm4+1] = v.y; Ft[c][mm4+2] = v.z; Ft[c][mm4+3] = v.w;
        }
    }

    float acc[8][8] = {};
    const int c0  = (t >> 3) * 8;   // 8 output channels per thread
    const int m0  = (t & 7) * 8;    // 8 output positions per thread
    const int sn2 = (t & 15) * 2;
    const int sm4 = (t >> 4) * 4;

    for (int n0 = 0; n0 < N_; n0 += 32) {
        __syncthreads();
        // stage Gt (64x32), Ht (256x32), Mn, rZn
        {
            const int nn4 = (t & 7) * 4;
            #pragma unroll
            for (int p = 0; p < 2; ++p) {
                const int c = (t >> 3) + p * 32;
                float4 v = *(const float4*)&go[((size_t)b * CQ_ + c) * N_ + n0 + nn4];
                Gt[c][nn4+0] = v.x; Gt[c][nn4+1] = v.y; Gt[c][nn4+2] = v.z; Gt[c][nn4+3] = v.w;
            }
            #pragma unroll
            for (int p = 0; p < 8; ++p) {
                const int c = (t >> 3) + p * 32;
                float4 v = *(const float4*)&ho[((size_t)b * C_ + c) * N_ + n0 + nn4];
                Ht[c][nn4+0] = v.x; Ht[c][nn4+1] = v.y; Ht[c][nn4+2] = v.z; Ht[c][nn4+3] = v.w;
            }
            if (t < 32) {
                Mn[t]  = Mw[(size_t)b * N_ + n0 + t];
                rZn[t] = 1.0f / Zw[(size_t)b * N_ + n0 + t];
            }
        }
        __syncthreads();
        // S tile [32 n][64 m] -> Pt = exp(S - M[n]) / Z[n]
        {
            float s[2][4] = {};
            #pragma unroll 8
            for (int c = 0; c < 64; ++c) {
                const float g0 = Gt[c][sn2+0], g1 = Gt[c][sn2+1];
                float4 fv = *(const float4*)&Ft[c][sm4];
                const float* fp = (const float*)&fv;
                #pragma unroll
                for (int j = 0; j < 4; ++j) {
                    s[0][j] = fmaf(g0, fp[j], s[0][j]);
                    s[1][j] = fmaf(g1, fp[j], s[1][j]);
                }
            }
            #pragma unroll
            for (int i = 0; i < 2; ++i) {
                const float mm = Mn[sn2+i], rz = rZn[sn2+i];
                #pragma unroll
                for (int j = 0; j < 4; ++j)
                    Pt[sn2+i][sm4+j] = __expf(s[i][j] - mm) * rz;
            }
        }
        __syncthreads();
        // o accumulation: acc[c][m] += Ht[c][nn] * Pt[nn][m]
        #pragma unroll 2
        for (int nn = 0; nn < 32; ++nn) {
            float4 pv0 = *(const float4*)&Pt[nn][m0];
            float4 pv1 = *(const float4*)&Pt[nn][m0+4];
            const float* p0 = (const float*)&pv0;
            const float* p1 = (const float*)&pv1;
            #pragma unroll
            for (int i = 0; i < 8; ++i) {
                const float hv = Ht[c0+i][nn];
                #pragma unroll
                for (int j = 0; j < 4; ++j) {
                    acc[i][j]   = fmaf(hv, p0[j], acc[i][j]);
                    acc[i][j+4] = fmaf(hv, p1[j], acc[i][j+4]);
                }
            }
        }
    }

    #pragma unroll
    for (int i = 0; i < 8; ++i) {
        const size_t idx = ((size_t)b * C_ + c0 + i) * N_ + mbase + m0;
        float4 x0 = *(const float4*)&x[idx];
        float4 x1 = *(const float4*)&x[idx + 4];
        float4 v0, v1;
        v0.x = fmaf(gamma, acc[i][0], x0.x);
        v0.y = fmaf(gamma, acc[i][1], x0.y);
        v0.z = fmaf(gamma, acc[i][2], x0.z);
        v0.w = fmaf(gamma, acc[i][3], x0.w);
        v1.x = fmaf(gamma, acc[i][4], x1.x);
        v1.y = fmaf(gamma, acc[i][5], x1.y);
        v1.z = fmaf(gamma, acc[i][6], x1.z);
        v1.w = fmaf(gamma, acc[i][7], x1.w);
        *(float4*)&out[idx]     = v0;
        *(float4*)&out[idx + 4] = v1;
    }
}

extern "C" void kernel_launch(void* const* d_in, const int* in_sizes, int n_in,
                              void* d_out, int out_size, void* d_ws, size_t ws_size,
                              hipStream_t stream)
{
    (void)in_sizes; (void)n_in; (void)out_size; (void)ws_size;
    const float* x     = (const float*)d_in[0];
    const float* Wf    = (const float*)d_in[1];
    const float* bf    = (const float*)d_in[2];
    const float* Wg    = (const float*)d_in[3];
    const float* bg    = (const float*)d_in[4];
    const float* Wh    = (const float*)d_in[5];
    const float* bh    = (const float*)d_in[6];
    const float* gamma = (const float*)d_in[7];
    float* out = (float*)d_out;

    float* f_ws = (float*)d_ws;                      // [B,CQ,N]
    float* g_ws = f_ws + (size_t)B_ * CQ_ * N_;      // [B,CQ,N]
    float* h_ws = g_ws + (size_t)B_ * CQ_ * N_;      // [B,C,N]
    float* M_ws = h_ws + (size_t)B_ * C_ * N_;       // [B,N]
    float* Z_ws = M_ws + (size_t)B_ * N_;            // [B,N]

    proj_kernel<<<dim3(N_/64, 6, B_), 256, 0, stream>>>(
        x, Wf, bf, Wg, bg, Wh, bh, f_ws, g_ws, h_ws);
    stats_kernel<<<dim3(N_/64, B_), 256, 0, stream>>>(
        f_ws, g_ws, M_ws, Z_ws);
    out_kernel<<<dim3(N_/64, B_), 256, 0, stream>>>(
        x, f_ws, g_ws, h_ws, M_ws, Z_ws, gamma, out);
}

// Round 2
// 200.414 us; speedup vs baseline: 3.9488x; 3.9488x over previous
//
#include <hip/hip_runtime.h>
#include <math.h>

#define B_  16
#define C_  256
#define N_  2048
#define CQ_ 64

typedef __attribute__((ext_vector_type(8))) short bf16x8;
typedef __attribute__((ext_vector_type(16))) float f32x16;

__device__ __forceinline__ unsigned short f2bf(float f) {
  union { float f; unsigned u; } v; v.f = f;
  unsigned r = v.u + 0x7FFFu + ((v.u >> 16) & 1u);
  return (unsigned short)(r >> 16);
}

__device__ __forceinline__ void gload16(const void* g, void* l) {
  __builtin_amdgcn_global_load_lds(
      (const __attribute__((address_space(1))) void*)g,
      (__attribute__((address_space(3))) void*)l, 16, 0, 0);
}

__device__ __forceinline__ f32x16 zero16() {
  f32x16 z;
  #pragma unroll
  for (int i = 0; i < 16; ++i) z[i] = 0.f;
  return z;
}

// fragment read from a [rows][64] bf16 LDS tile with 16B-chunk XOR swizzle:
// chunk' = chunk ^ (row&7); fragment k-chunk = 2*kb + hi
__device__ __forceinline__ bf16x8 frag_ld(const unsigned short* base, int row, int kb, int hi) {
  const int byteoff = row * 128 + ((((kb << 1) + hi) ^ (row & 7)) << 4);
  return *(const bf16x8*)((const char*)base + byteoff);
}

// ---------------- Kernel 1: projections (fp32 VALU) -> bf16 swizzled outputs
// f,g stored transposed [b][n][c] (chunk ^= n&7); h stored [b][c][n] with
// per-64n-group chunk ^= c&7.  Grid: (N/64, 6, B), 256 threads.
__global__ __launch_bounds__(256) void proj_kernel(
    const float* __restrict__ x,
    const float* __restrict__ Wf, const float* __restrict__ bf,
    const float* __restrict__ Wg, const float* __restrict__ bg,
    const float* __restrict__ Wh, const float* __restrict__ bh,
    unsigned short* __restrict__ f_t, unsigned short* __restrict__ g_t,
    unsigned short* __restrict__ h_sw)
{
    const int b  = blockIdx.z;
    const int og = blockIdx.y;
    const int nbase = blockIdx.x * 64;
    const float* W; const float* bias; int orow;
    if (og == 0)      { W = Wf; bias = bf; orow = 0; }
    else if (og == 1) { W = Wg; bias = bg; orow = 0; }
    else              { W = Wh; bias = bh; orow = (og-2)*64; }

    __shared__ float Wt[64][68];
    __shared__ float Xt[64][68];

    const int t  = threadIdx.x;
    const int to = (t >> 4) * 4;
    const int tn = (t & 15) * 4;

    float acc[4][4] = {};

    for (int k0 = 0; k0 < C_; k0 += 64) {
        __syncthreads();
        #pragma unroll
        for (int p = 0; p < 4; ++p) {
            const int r  = (t >> 4) + p * 16;
            const int cc = (t & 15) * 4;
            float4 w4 = *(const float4*)&W[(size_t)(orow + r) * C_ + k0 + cc];
            Wt[cc+0][r] = w4.x; Wt[cc+1][r] = w4.y; Wt[cc+2][r] = w4.z; Wt[cc+3][r] = w4.w;
            float4 x4 = *(const float4*)&x[((size_t)b * C_ + k0 + r) * N_ + nbase + cc];
            *(float4*)&Xt[r][cc] = x4;
        }
        __syncthreads();
        #pragma unroll 16
        for (int kk = 0; kk < 64; ++kk) {
            float4 wv = *(const float4*)&Wt[kk][to];
            float4 xv = *(const float4*)&Xt[kk][tn];
            const float* wp = (const float*)&wv;
            const float* xp = (const float*)&xv;
            #pragma unroll
            for (int i = 0; i < 4; ++i)
                #pragma unroll
                for (int j = 0; j < 4; ++j)
                    acc[i][j] = fmaf(wp[i], xp[j], acc[i][j]);
        }
    }

    const float b0 = bias[orow + to + 0];
    const float b1 = bias[orow + to + 1];
    const float b2 = bias[orow + to + 2];
    const float b3 = bias[orow + to + 3];

    if (og < 2) {
        unsigned short* y = (og == 0) ? f_t : g_t;
        #pragma unroll
        for (int j = 0; j < 4; ++j) {
            const int nl = tn + j;
            const int c2 = ((((to >> 3) ^ (nl & 7)) << 3) | (to & 7));
            ushort4 u;
            u.x = f2bf(fmaxf(acc[0][j] + b0, 0.f));
            u.y = f2bf(fmaxf(acc[1][j] + b1, 0.f));
            u.z = f2bf(fmaxf(acc[2][j] + b2, 0.f));
            u.w = f2bf(fmaxf(acc[3][j] + b3, 0.f));
            *(ushort4*)&y[((size_t)b * N_ + nbase + nl) * CQ_ + c2] = u;
        }
    } else {
        const float bb[4] = {b0, b1, b2, b3};
        #pragma unroll
        for (int i = 0; i < 4; ++i) {
            const int o  = orow + to + i;
            const int n2 = ((((tn >> 3) ^ (o & 7)) << 3) | (tn & 7));
            ushort4 u;
            u.x = f2bf(fmaxf(acc[i][0] + bb[i], 0.f));
            u.y = f2bf(fmaxf(acc[i][1] + bb[i], 0.f));
            u.z = f2bf(fmaxf(acc[i][2] + bb[i], 0.f));
            u.w = f2bf(fmaxf(acc[i][3] + bb[i], 0.f));
            *(ushort4*)&h_sw[((size_t)b * C_ + o) * N_ + nbase + n2] = u;
        }
    }
}

// ---------------- Kernel 2: row stats via MFMA --------------------------------
// S^T[m][n] tiles (A=f frag, B=g frag); per-lane col=n; online max/sum over m.
// Grid: (N/64, B), 256 threads (4 waves).
__global__ __launch_bounds__(256) void stats_kernel(
    const unsigned short* __restrict__ f_t, const unsigned short* __restrict__ g_t,
    float* __restrict__ Mw, float* __restrict__ rZw)
{
    const int b  = blockIdx.y;
    const int nb = blockIdx.x * 64;

    __shared__ __align__(16) unsigned short G_lds[64*64];
    __shared__ __align__(16) unsigned short F_lds[64*64];
    __shared__ float pM[2][64];
    __shared__ float pZ[2][64];

    const int t = threadIdx.x;
    const int w = t >> 6, lane = t & 63, hi = lane >> 5, ln = lane & 31;
    const int mb = w >> 1, nb2 = w & 1;

    {
        const char* gsrc = (const char*)(g_t + ((size_t)b * N_ + nb) * CQ_);
        #pragma unroll
        for (int p = 0; p < 2; ++p) {
            const int off = (w * 2 + p) * 1024;
            gload16(gsrc + off + lane * 16, (char*)G_lds + off);
        }
    }

    float runM = -1e30f, runZ = 0.f;

    for (int s = 0; s < N_ / 64; ++s) {
        const char* fsrc = (const char*)(f_t + ((size_t)b * N_ + s * 64) * CQ_);
        #pragma unroll
        for (int p = 0; p < 2; ++p) {
            const int off = (w * 2 + p) * 1024;
            gload16(fsrc + off + lane * 16, (char*)F_lds + off);
        }
        __syncthreads();

        f32x16 sacc = zero16();
        #pragma unroll
        for (int kb = 0; kb < 4; ++kb) {
            bf16x8 a  = frag_ld(F_lds, mb * 32 + ln, kb, hi);
            bf16x8 g8 = frag_ld(G_lds, nb2 * 32 + ln, kb, hi);
            sacc = __builtin_amdgcn_mfma_f32_32x32x16_bf16(a, g8, sacc, 0, 0, 0);
        }

        float lm = sacc[0];
        #pragma unroll
        for (int r = 1; r < 16; ++r) lm = fmaxf(lm, sacc[r]);
        const float nm = fmaxf(runM, lm);
        float ssum = 0.f;
        #pragma unroll
        for (int r = 0; r < 16; ++r) ssum += __expf(sacc[r] - nm);
        runZ = runZ * __expf(runM - nm) + ssum;
        runM = nm;
        __syncthreads();
    }

    // combine lane<->lane^32 (complementary rows)
    {
        const float oM = __shfl_xor(runM, 32);
        const float oZ = __shfl_xor(runZ, 32);
        const float Mf = fmaxf(runM, oM);
        const float Zf = runZ * __expf(runM - Mf) + oZ * __expf(oM - Mf);
        if (lane < 32) { pM[mb][nb2 * 32 + lane] = Mf; pZ[mb][nb2 * 32 + lane] = Zf; }
    }
    __syncthreads();
    if (t < 64) {
        const float m0 = pM[0][t], m1 = pM[1][t];
        const float M  = fmaxf(m0, m1);
        const float Z  = pZ[0][t] * __expf(m0 - M) + pZ[1][t] * __expf(m1 - M);
        Mw[(size_t)b * N_ + nb + t]  = M;
        rZw[(size_t)b * N_ + nb + t] = 1.0f / Z;
    }
}

// ---------------- Kernel 3: fused S-recompute + softmax + O GEMM + residual --
// Grid: (N/128, B), 512 threads (8 waves). Block tile: 256c x 128m, n-loop 64.
__global__ __launch_bounds__(512) void out_kernel(
    const float* __restrict__ x,
    const unsigned short* __restrict__ f_t, const unsigned short* __restrict__ g_t,
    const unsigned short* __restrict__ h_sw,
    const float* __restrict__ Mw, const float* __restrict__ rZw,
    const float* __restrict__ gamma_p, float* __restrict__ out)
{
    const int b = blockIdx.y;
    const int mbase = blockIdx.x * 128;

    __shared__ __align__(16) unsigned short F_lds[128*64];     // 16 KB
    __shared__ __align__(16) unsigned short G_lds[2][64*64];   // 16 KB
    __shared__ __align__(16) unsigned short H_lds[2][256*64];  // 64 KB
    __shared__ __align__(16) unsigned short P_lds[128*64];     // 16 KB
    __shared__ __align__(16) float M_lds[N_];                  // 8 KB
    __shared__ __align__(16) float Z_lds[N_];                  // 8 KB

    const int t = threadIdx.x;
    const int w = t >> 6, lane = t & 63, hi = lane >> 5, ln = lane & 31;
    const int amb = w & 3, anb = w >> 2;   // stage-A: m-block(32), n-block(32)
    const int cb  = w & 3, mbw = w >> 2;   // stage-B: c-block(64), m-block(64)

    auto STAGE = [&](int tt, int buf) {
        const char* gsrc = (const char*)(g_t + ((size_t)b * N_ + tt * 64) * CQ_);
        gload16(gsrc + w * 1024 + lane * 16, (char*)&G_lds[buf][0] + w * 1024);
        const char* hsrc = (const char*)h_sw + ((size_t)b * C_) * (N_ * 2) + (size_t)tt * 128;
        #pragma unroll
        for (int p = 0; p < 4; ++p) {
            const int c0 = w * 32 + p * 8;
            gload16(hsrc + (size_t)(c0 + (lane >> 3)) * (N_ * 2) + (lane & 7) * 16,
                    (char*)&H_lds[buf][0] + c0 * 128);
        }
    };

    // prologue staging: F (16KB), M (8KB), Z (8KB), tile 0
    {
        const char* fsrc = (const char*)(f_t + ((size_t)b * N_ + mbase) * CQ_);
        gload16(fsrc + w * 2048 + lane * 16, (char*)F_lds + w * 2048);
        gload16(fsrc + w * 2048 + 1024 + lane * 16, (char*)F_lds + w * 2048 + 1024);
        const char* msrc = (const char*)(Mw + (size_t)b * N_);
        gload16(msrc + w * 1024 + lane * 16, (char*)M_lds + w * 1024);
        const char* zsrc = (const char*)(rZw + (size_t)b * N_);
        gload16(zsrc + w * 1024 + lane * 16, (char*)Z_lds + w * 1024);
        STAGE(0, 0);
    }
    __syncthreads();

    f32x16 acc00 = zero16(), acc01 = zero16(), acc10 = zero16(), acc11 = zero16();

    for (int tt = 0; tt < N_ / 64; ++tt) {
        const int cur = tt & 1;

        // ---- stage-A: S^T tile [32m x 32n] per wave, exp -> P_lds
        f32x16 sacc = zero16();
        #pragma unroll
        for (int kb = 0; kb < 4; ++kb) {
            bf16x8 a  = frag_ld(F_lds, amb * 32 + ln, kb, hi);
            bf16x8 g8 = frag_ld(&G_lds[cur][0], anb * 32 + ln, kb, hi);
            sacc = __builtin_amdgcn_mfma_f32_32x32x16_bf16(a, g8, sacc, 0, 0, 0);
        }
        const int nloc = anb * 32 + ln;
        const float Mv  = M_lds[tt * 64 + nloc];
        const float rZv = Z_lds[tt * 64 + nloc];
        #pragma unroll
        for (int r = 0; r < 16; ++r) {
            const int m = amb * 32 + (r & 3) + ((r >> 2) << 3) + (hi << 2);
            const float p = __expf(sacc[r] - Mv) * rZv;
            *(unsigned short*)((char*)P_lds + m * 128 +
                ((((nloc >> 3) ^ (m & 7)) << 4) | ((nloc & 7) << 1))) = f2bf(p);
        }
        __syncthreads();   // P ready

        if (tt + 1 < N_ / 64) STAGE(tt + 1, cur ^ 1);

        // ---- stage-B: acc[64c x 64m] += H[64c x 64n] * P[64n x 64m]
        #pragma unroll
        for (int kb = 0; kb < 4; ++kb) {
            bf16x8 ha0 = frag_ld(&H_lds[cur][0], cb * 64 + ln,      kb, hi);
            bf16x8 ha1 = frag_ld(&H_lds[cur][0], cb * 64 + 32 + ln, kb, hi);
            bf16x8 pb0 = frag_ld(P_lds, mbw * 64 + ln,      kb, hi);
            bf16x8 pb1 = frag_ld(P_lds, mbw * 64 + 32 + ln, kb, hi);
            acc00 = __builtin_amdgcn_mfma_f32_32x32x16_bf16(ha0, pb0, acc00, 0, 0, 0);
            acc01 = __builtin_amdgcn_mfma_f32_32x32x16_bf16(ha0, pb1, acc01, 0, 0, 0);
            acc10 = __builtin_amdgcn_mfma_f32_32x32x16_bf16(ha1, pb0, acc10, 0, 0, 0);
            acc11 = __builtin_amdgcn_mfma_f32_32x32x16_bf16(ha1, pb1, acc11, 0, 0, 0);
        }
        __syncthreads();   // P consumable next iter; next-tile stage drained
    }

    // ---- epilogue: out = gamma*o + x
    const float gamma = gamma_p[0];
    #pragma unroll
    for (int ci = 0; ci < 2; ++ci) {
        #pragma unroll
        for (int mi = 0; mi < 2; ++mi) {
            const f32x16& a = (ci == 0) ? (mi == 0 ? acc00 : acc01)
                                        : (mi == 0 ? acc10 : acc11);
            #pragma unroll
            for (int r = 0; r < 16; ++r) {
                const int c = cb * 64 + ci * 32 + (r & 3) + ((r >> 2) << 3) + (hi << 2);
                const int m = mbase + mbw * 64 + mi * 32 + ln;
                const size_t idx = ((size_t)b * C_ + c) * N_ + m;
                out[idx] = fmaf(gamma, a[r], x[idx]);
            }
        }
    }
}

extern "C" void kernel_launch(void* const* d_in, const int* in_sizes, int n_in,
                              void* d_out, int out_size, void* d_ws, size_t ws_size,
                              hipStream_t stream)
{
    (void)in_sizes; (void)n_in; (void)out_size; (void)ws_size;
    const float* x     = (const float*)d_in[0];
    const float* Wf    = (const float*)d_in[1];
    const float* bf    = (const float*)d_in[2];
    const float* Wg    = (const float*)d_in[3];
    const float* bg    = (const float*)d_in[4];
    const float* Wh    = (const float*)d_in[5];
    const float* bh    = (const float*)d_in[6];
    const float* gamma = (const float*)d_in[7];
    float* out = (float*)d_out;

    unsigned short* f_t  = (unsigned short*)d_ws;                 // [B][N][CQ] bf16 swz
    unsigned short* g_t  = f_t + (size_t)B_ * N_ * CQ_;           // [B][N][CQ] bf16 swz
    unsigned short* h_sw = g_t + (size_t)B_ * N_ * CQ_;           // [B][C][N]  bf16 swz
    float* M_ws  = (float*)(h_sw + (size_t)B_ * C_ * N_);         // [B][N]
    float* rZ_ws = M_ws + (size_t)B_ * N_;                        // [B][N]

    proj_kernel<<<dim3(N_/64, 6, B_), 256, 0, stream>>>(
        x, Wf, bf, Wg, bg, Wh, bh, f_t, g_t, h_sw);
    stats_kernel<<<dim3(N_/64, B_), 256, 0, stream>>>(
        f_t, g_t, M_ws, rZ_ws);
    out_kernel<<<dim3(N_/128, B_), 512, 0, stream>>>(
        x, f_t, g_t, h_sw, M_ws, rZ_ws, gamma, out);
}

// Round 3
// 141.096 us; speedup vs baseline: 5.6090x; 1.4204x over previous
//
#include <hip/hip_runtime.h>
#include <math.h>

#define B_  16
#define C_  256
#define N_  2048
#define CQ_ 64

typedef __attribute__((ext_vector_type(8))) short bf16x8;
typedef __attribute__((ext_vector_type(8))) unsigned short u16x8;
typedef __attribute__((ext_vector_type(16))) float f32x16;

__device__ __forceinline__ unsigned short f2bf(float f) {
  union { float f; unsigned u; } v; v.f = f;
  unsigned r = v.u + 0x7FFFu + ((v.u >> 16) & 1u);
  return (unsigned short)(r >> 16);
}

__device__ __forceinline__ void gload16(const void* g, void* l) {
  __builtin_amdgcn_global_load_lds(
      (const __attribute__((address_space(1))) void*)g,
      (__attribute__((address_space(3))) void*)l, 16, 0, 0);
}

__device__ __forceinline__ f32x16 zero16() {
  f32x16 z;
  #pragma unroll
  for (int i = 0; i < 16; ++i) z[i] = 0.f;
  return z;
}

// fragment read from a [rows][64] bf16 LDS tile with 16B-chunk XOR swizzle:
// chunk' = chunk ^ (row&7); fragment k-chunk = 2*kb + hi
__device__ __forceinline__ bf16x8 frag_ld(const unsigned short* base, int row, int kb, int hi) {
  const int byteoff = row * 128 + ((((kb << 1) + hi) ^ (row & 7)) << 4);
  return *(const bf16x8*)((const char*)base + byteoff);
}

// ---------------- Kernel 0a: pack weights -> bf16 swizzled Wall[384][256] ----
__global__ __launch_bounds__(256) void pack_kernel(
    const float* __restrict__ Wf, const float* __restrict__ bf,
    const float* __restrict__ Wg, const float* __restrict__ bg,
    const float* __restrict__ Wh, const float* __restrict__ bh,
    unsigned short* __restrict__ Wall, float* __restrict__ ball)
{
    const int t = threadIdx.x;
    const int o = blockIdx.x * 64 + (t >> 2);
    const int cq = (t & 3) * 64;
    const float* W; const float* bias; int r;
    if (o < 64)       { W = Wf; bias = bf; r = o; }
    else if (o < 128) { W = Wg; bias = bg; r = o - 64; }
    else              { W = Wh; bias = bh; r = o - 128; }
    for (int j = 0; j < 64; ++j) {
        const int c = cq + j;
        const int chunk = ((c >> 3) & 7) ^ (o & 7);
        Wall[(size_t)o * 256 + (c & ~63) + chunk * 8 + (c & 7)] = f2bf(W[(size_t)r * 256 + c]);
    }
    if ((t & 3) == 0) ball[o] = bias[r];
}

// ---------------- Kernel 0b: x [b][c][n] fp32 -> x_t [b][n][c] bf16 swz ------
__global__ __launch_bounds__(256) void xT_kernel(
    const float* __restrict__ x, unsigned short* __restrict__ x_t)
{
    const int b = blockIdx.z, g = blockIdx.y, n0 = blockIdx.x * 64;
    __shared__ float T[64][65];
    const int t = threadIdx.x;
    {
        const int c = t >> 4, n4 = (t & 15) * 4;
        #pragma unroll
        for (int p = 0; p < 4; ++p) {
            float4 v = *(const float4*)&x[((size_t)b * C_ + g * 64 + c + p * 16) * N_ + n0 + n4];
            T[c + p*16][n4+0] = v.x; T[c + p*16][n4+1] = v.y;
            T[c + p*16][n4+2] = v.z; T[c + p*16][n4+3] = v.w;
        }
    }
    __syncthreads();
    const int n = t >> 2, c16 = (t & 3) * 16;
    unsigned short* dst = x_t + ((size_t)b * N_ + n0 + n) * 256 + g * 64;
    #pragma unroll
    for (int k = 0; k < 2; ++k) {
        u16x8 v;
        #pragma unroll
        for (int j = 0; j < 8; ++j) v[j] = f2bf(T[c16 + k*8 + j][n]);
        const int ch = ((c16 >> 3) + k) ^ (n & 7);
        *(u16x8*)&dst[ch * 8] = v;
    }
}

// ---------------- Kernel 1: projections via MFMA -----------------------------
// Y[384][2048] per batch; tile 128o x 128n, K=256. Flat grid 768, XCD-swizzled.
__global__ __launch_bounds__(256) void projmm_kernel(
    const unsigned short* __restrict__ Wall, const float* __restrict__ ball,
    const unsigned short* __restrict__ x_t,
    unsigned short* __restrict__ f_t, unsigned short* __restrict__ g_t,
    unsigned short* __restrict__ h_sw)
{
    const int L = blockIdx.x;
    const int slot = L >> 3;                       // 0..95
    const int b  = (L & 7) + (slot >= 48 ? 8 : 0); // same batch -> same XCD
    const int id2 = (slot >= 48) ? slot - 48 : slot;
    const int ot = id2 % 3, nt = id2 / 3;

    __shared__ __align__(16) unsigned short LDSbuf[2][128 * 64]; // 2 x 16KB
    __shared__ float biasS[128];

    const int t = threadIdx.x, w = t >> 6, lane = t & 63, hi = lane >> 5, ln = lane & 31;
    const int oh = w & 1, nh = w >> 1;

    if (t < 128) biasS[t] = ball[ot * 128 + t];

    f32x16 a00 = zero16(), a01 = zero16(), a10 = zero16(), a11 = zero16();

    for (int k = 0; k < 4; ++k) {
        __syncthreads();   // prev compute done (and biasS visible after 1st)
        #pragma unroll
        for (int p = 0; p < 4; ++p) {
            const int q = p * 256 + t, r = q >> 3, cc = q & 7;
            gload16((const char*)Wall + ((size_t)(ot*128 + r) * 256 + k*64 + cc*8) * 2,
                    (char*)&LDSbuf[0][0] + q * 16);
            gload16((const char*)x_t + (((size_t)b * N_ + nt*128 + r) * 256 + k*64 + cc*8) * 2,
                    (char*)&LDSbuf[1][0] + q * 16);
        }
        __syncthreads();   // staging drained
        #pragma unroll
        for (int kb = 0; kb < 4; ++kb) {
            bf16x8 w0 = frag_ld(&LDSbuf[0][0], oh*64 + ln,      kb, hi);
            bf16x8 w1 = frag_ld(&LDSbuf[0][0], oh*64 + 32 + ln, kb, hi);
            bf16x8 x0 = frag_ld(&LDSbuf[1][0], nh*64 + ln,      kb, hi);
            bf16x8 x1 = frag_ld(&LDSbuf[1][0], nh*64 + 32 + ln, kb, hi);
            a00 = __builtin_amdgcn_mfma_f32_32x32x16_bf16(w0, x0, a00, 0, 0, 0);
            a01 = __builtin_amdgcn_mfma_f32_32x32x16_bf16(w0, x1, a01, 0, 0, 0);
            a10 = __builtin_amdgcn_mfma_f32_32x32x16_bf16(w1, x0, a10, 0, 0, 0);
            a11 = __builtin_amdgcn_mfma_f32_32x32x16_bf16(w1, x1, a11, 0, 0, 0);
        }
    }

    if (ot == 0) {
        // rows 0..63 = f, 64..127 = g ; layout [b][n][c-swz]
        unsigned short* y = (oh == 0) ? f_t : g_t;
        #pragma unroll
        for (int j = 0; j < 2; ++j) {
            const int n = nh*64 + j*32 + ln;
            #pragma unroll
            for (int i = 0; i < 2; ++i) {
                const f32x16& a = (i == 0) ? (j == 0 ? a00 : a01)
                                           : (j == 0 ? a10 : a11);
                #pragma unroll
                for (int q = 0; q < 4; ++q) {
                    const int c0 = i*32 + q*8 + 4*hi;
                    ushort4 u;
                    u.x = f2bf(fmaxf(a[q*4+0] + biasS[oh*64 + c0 + 0], 0.f));
                    u.y = f2bf(fmaxf(a[q*4+1] + biasS[oh*64 + c0 + 1], 0.f));
                    u.z = f2bf(fmaxf(a[q*4+2] + biasS[oh*64 + c0 + 2], 0.f));
                    u.w = f2bf(fmaxf(a[q*4+3] + biasS[oh*64 + c0 + 3], 0.f));
                    *(ushort4*)&y[((size_t)b * N_ + nt*128 + n) * CQ_ +
                                  ((((c0 >> 3) ^ (n & 7)) << 3) + 4*hi)] = u;
                }
            }
        }
    } else {
        // h rows: transpose via LDS; store-side swizzle == global swizzle
        __syncthreads();   // all frag reads of LDSbuf done
        unsigned short* Ht = &LDSbuf[0][0];   // 128 x 128 bf16 = 32KB
        #pragma unroll
        for (int j = 0; j < 2; ++j) {
            const int n_lo = nh*64 + j*32 + ln;
            const int chunk = n_lo >> 3;
            #pragma unroll
            for (int i = 0; i < 2; ++i) {
                const f32x16& a = (i == 0) ? (j == 0 ? a00 : a01)
                                           : (j == 0 ? a10 : a11);
                #pragma unroll
                for (int r = 0; r < 16; ++r) {
                    const int o_lo = oh*64 + i*32 + (r & 3) + ((r >> 2) << 3) + 4*hi;
                    const int chs = (chunk & 8) | ((chunk ^ o_lo) & 7);
                    Ht[o_lo * 128 + chs * 8 + (n_lo & 7)] =
                        f2bf(fmaxf(a[r] + biasS[o_lo], 0.f));
                }
            }
        }
        __syncthreads();
        const int o_l = t >> 1, half = t & 1;
        const int c = (ot - 1) * 128 + o_l;
        unsigned short* dst = h_sw + ((size_t)b * C_ + c) * N_ + (nt*2 + half) * 64;
        const unsigned short* src = Ht + o_l * 128 + half * 64;
        #pragma unroll
        for (int c8 = 0; c8 < 8; ++c8)
            *(u16x8*)&dst[c8 * 8] = *(const u16x8*)&src[c8 * 8];
    }
}

// ---------------- Kernel 2: row stats via MFMA -------------------------------
__global__ __launch_bounds__(256) void stats_kernel(
    const unsigned short* __restrict__ f_t, const unsigned short* __restrict__ g_t,
    float* __restrict__ Mw, float* __restrict__ rZw)
{
    const int L = blockIdx.x;
    const int slot = L >> 3;                       // 0..63
    const int b  = (L & 7) + (slot >= 32 ? 8 : 0);
    const int nb = ((slot >= 32) ? slot - 32 : slot) * 64;

    __shared__ __align__(16) unsigned short G_lds[64*64];
    __shared__ __align__(16) unsigned short F_lds[64*64];
    __shared__ float pM[2][64];
    __shared__ float pZ[2][64];

    const int t = threadIdx.x;
    const int w = t >> 6, lane = t & 63, hi = lane >> 5, ln = lane & 31;
    const int mb = w >> 1, nb2 = w & 1;

    {
        const char* gsrc = (const char*)(g_t + ((size_t)b * N_ + nb) * CQ_);
        #pragma unroll
        for (int p = 0; p < 2; ++p) {
            const int off = (w * 2 + p) * 1024;
            gload16(gsrc + off + lane * 16, (char*)G_lds + off);
        }
    }

    float runM = -1e30f, runZ = 0.f;

    for (int s = 0; s < N_ / 64; ++s) {
        const char* fsrc = (const char*)(f_t + ((size_t)b * N_ + s * 64) * CQ_);
        #pragma unroll
        for (int p = 0; p < 2; ++p) {
            const int off = (w * 2 + p) * 1024;
            gload16(fsrc + off + lane * 16, (char*)F_lds + off);
        }
        __syncthreads();

        f32x16 sacc = zero16();
        #pragma unroll
        for (int kb = 0; kb < 4; ++kb) {
            bf16x8 a  = frag_ld(F_lds, mb * 32 + ln, kb, hi);
            bf16x8 g8 = frag_ld(G_lds, nb2 * 32 + ln, kb, hi);
            sacc = __builtin_amdgcn_mfma_f32_32x32x16_bf16(a, g8, sacc, 0, 0, 0);
        }

        float lm = sacc[0];
        #pragma unroll
        for (int r = 1; r < 16; ++r) lm = fmaxf(lm, sacc[r]);
        const float nm = fmaxf(runM, lm);
        float ssum = 0.f;
        #pragma unroll
        for (int r = 0; r < 16; ++r) ssum += __expf(sacc[r] - nm);
        runZ = runZ * __expf(runM - nm) + ssum;
        runM = nm;
        __syncthreads();
    }

    {
        const float oM = __shfl_xor(runM, 32);
        const float oZ = __shfl_xor(runZ, 32);
        const float Mf = fmaxf(runM, oM);
        const float Zf = runZ * __expf(runM - Mf) + oZ * __expf(oM - Mf);
        if (lane < 32) { pM[mb][nb2 * 32 + lane] = Mf; pZ[mb][nb2 * 32 + lane] = Zf; }
    }
    __syncthreads();
    if (t < 64) {
        const float m0 = pM[0][t], m1 = pM[1][t];
        const float M  = fmaxf(m0, m1);
        const float Z  = pZ[0][t] * __expf(m0 - M) + pZ[1][t] * __expf(m1 - M);
        Mw[(size_t)b * N_ + nb + t]  = M;
        rZw[(size_t)b * N_ + nb + t] = 1.0f / Z;
    }
}

// ---------------- Kernel 3: fused S-recompute + softmax + O GEMM + residual --
__global__ __launch_bounds__(512) void out_kernel(
    const float* __restrict__ x,
    const unsigned short* __restrict__ f_t, const unsigned short* __restrict__ g_t,
    const unsigned short* __restrict__ h_sw,
    const float* __restrict__ Mw, const float* __restrict__ rZw,
    const float* __restrict__ gamma_p, float* __restrict__ out)
{
    const int L = blockIdx.x;
    const int slot = L >> 3;                       // 0..31
    const int b = (L & 7) + (slot >= 16 ? 8 : 0);
    const int mbase = ((slot >= 16) ? slot - 16 : slot) * 128;

    __shared__ __align__(16) unsigned short F_lds[128*64];
    __shared__ __align__(16) unsigned short G_lds[2][64*64];
    __shared__ __align__(16) unsigned short H_lds[2][256*64];
    __shared__ __align__(16) unsigned short P_lds[128*64];
    __shared__ __align__(16) float M_lds[N_];
    __shared__ __align__(16) float Z_lds[N_];

    const int t = threadIdx.x;
    const int w = t >> 6, lane = t & 63, hi = lane >> 5, ln = lane & 31;
    const int amb = w & 3, anb = w >> 2;
    const int cb  = w & 3, mbw = w >> 2;

    auto STAGE = [&](int tt, int buf) {
        const char* gsrc = (const char*)(g_t + ((size_t)b * N_ + tt * 64) * CQ_);
        gload16(gsrc + w * 1024 + lane * 16, (char*)&G_lds[buf][0] + w * 1024);
        const char* hsrc = (const char*)h_sw + ((size_t)b * C_) * (N_ * 2) + (size_t)tt * 128;
        #pragma unroll
        for (int p = 0; p < 4; ++p) {
            const int c0 = w * 32 + p * 8;
            gload16(hsrc + (size_t)(c0 + (lane >> 3)) * (N_ * 2) + (lane & 7) * 16,
                    (char*)&H_lds[buf][0] + c0 * 128);
        }
    };

    {
        const char* fsrc = (const char*)(f_t + ((size_t)b * N_ + mbase) * CQ_);
        gload16(fsrc + w * 2048 + lane * 16, (char*)F_lds + w * 2048);
        gload16(fsrc + w * 2048 + 1024 + lane * 16, (char*)F_lds + w * 2048 + 1024);
        const char* msrc = (const char*)(Mw + (size_t)b * N_);
        gload16(msrc + w * 1024 + lane * 16, (char*)M_lds + w * 1024);
        const char* zsrc = (const char*)(rZw + (size_t)b * N_);
        gload16(zsrc + w * 1024 + lane * 16, (char*)Z_lds + w * 1024);
        STAGE(0, 0);
    }
    __syncthreads();

    f32x16 acc00 = zero16(), acc01 = zero16(), acc10 = zero16(), acc11 = zero16();

    for (int tt = 0; tt < N_ / 64; ++tt) {
        const int cur = tt & 1;

        f32x16 sacc = zero16();
        #pragma unroll
        for (int kb = 0; kb < 4; ++kb) {
            bf16x8 a  = frag_ld(F_lds, amb * 32 + ln, kb, hi);
            bf16x8 g8 = frag_ld(&G_lds[cur][0], anb * 32 + ln, kb, hi);
            sacc = __builtin_amdgcn_mfma_f32_32x32x16_bf16(a, g8, sacc, 0, 0, 0);
        }
        const int nloc = anb * 32 + ln;
        const float Mv  = M_lds[tt * 64 + nloc];
        const float rZv = Z_lds[tt * 64 + nloc];
        #pragma unroll
        for (int r = 0; r < 16; ++r) {
            const int m = amb * 32 + (r & 3) + ((r >> 2) << 3) + (hi << 2);
            const float p = __expf(sacc[r] - Mv) * rZv;
            *(unsigned short*)((char*)P_lds + m * 128 +
                ((((nloc >> 3) ^ (m & 7)) << 4) | ((nloc & 7) << 1))) = f2bf(p);
        }
        __syncthreads();

        if (tt + 1 < N_ / 64) STAGE(tt + 1, cur ^ 1);

        #pragma unroll
        for (int kb = 0; kb < 4; ++kb) {
            bf16x8 ha0 = frag_ld(&H_lds[cur][0], cb * 64 + ln,      kb, hi);
            bf16x8 ha1 = frag_ld(&H_lds[cur][0], cb * 64 + 32 + ln, kb, hi);
            bf16x8 pb0 = frag_ld(P_lds, mbw * 64 + ln,      kb, hi);
            bf16x8 pb1 = frag_ld(P_lds, mbw * 64 + 32 + ln, kb, hi);
            acc00 = __builtin_amdgcn_mfma_f32_32x32x16_bf16(ha0, pb0, acc00, 0, 0, 0);
            acc01 = __builtin_amdgcn_mfma_f32_32x32x16_bf16(ha0, pb1, acc01, 0, 0, 0);
            acc10 = __builtin_amdgcn_mfma_f32_32x32x16_bf16(ha1, pb0, acc10, 0, 0, 0);
            acc11 = __builtin_amdgcn_mfma_f32_32x32x16_bf16(ha1, pb1, acc11, 0, 0, 0);
        }
        __syncthreads();
    }

    const float gamma = gamma_p[0];
    #pragma unroll
    for (int ci = 0; ci < 2; ++ci) {
        #pragma unroll
        for (int mi = 0; mi < 2; ++mi) {
            const f32x16& a = (ci == 0) ? (mi == 0 ? acc00 : acc01)
                                        : (mi == 0 ? acc10 : acc11);
            #pragma unroll
            for (int r = 0; r < 16; ++r) {
                const int c = cb * 64 + ci * 32 + (r & 3) + ((r >> 2) << 3) + (hi << 2);
                const int m = mbase + mbw * 64 + mi * 32 + ln;
                const size_t idx = ((size_t)b * C_ + c) * N_ + m;
                out[idx] = fmaf(gamma, a[r], x[idx]);
            }
        }
    }
}

extern "C" void kernel_launch(void* const* d_in, const int* in_sizes, int n_in,
                              void* d_out, int out_size, void* d_ws, size_t ws_size,
                              hipStream_t stream)
{
    (void)in_sizes; (void)n_in; (void)out_size; (void)ws_size;
    const float* x     = (const float*)d_in[0];
    const float* Wf    = (const float*)d_in[1];
    const float* bf    = (const float*)d_in[2];
    const float* Wg    = (const float*)d_in[3];
    const float* bg    = (const float*)d_in[4];
    const float* Wh    = (const float*)d_in[5];
    const float* bh    = (const float*)d_in[6];
    const float* gamma = (const float*)d_in[7];
    float* out = (float*)d_out;

    unsigned short* f_t  = (unsigned short*)d_ws;                 // [B][N][CQ] bf16 swz
    unsigned short* g_t  = f_t + (size_t)B_ * N_ * CQ_;           // [B][N][CQ] bf16 swz
    unsigned short* h_sw = g_t + (size_t)B_ * N_ * CQ_;           // [B][C][N]  bf16 swz
    float* M_ws  = (float*)(h_sw + (size_t)B_ * C_ * N_);         // [B][N]
    float* rZ_ws = M_ws + (size_t)B_ * N_;                        // [B][N]
    unsigned short* x_t  = (unsigned short*)(rZ_ws + (size_t)B_ * N_); // [B][N][C] bf16 swz
    unsigned short* Wall = x_t + (size_t)B_ * N_ * C_;            // [384][256] bf16 swz
    float* ball  = (float*)(Wall + (size_t)384 * 256);            // [384]

    pack_kernel<<<dim3(6), 256, 0, stream>>>(Wf, bf, Wg, bg, Wh, bh, Wall, ball);
    xT_kernel<<<dim3(N_/64, C_/64, B_), 256, 0, stream>>>(x, x_t);
    projmm_kernel<<<dim3(768), 256, 0, stream>>>(Wall, ball, x_t, f_t, g_t, h_sw);
    stats_kernel<<<dim3(512), 256, 0, stream>>>(f_t, g_t, M_ws, rZ_ws);
    out_kernel<<<dim3(256), 512, 0, stream>>>(x, f_t, g_t, h_sw, M_ws, rZ_ws, gamma, out);
}

// Round 4
// 136.708 us; speedup vs baseline: 5.7890x; 1.0321x over previous
//
#include <hip/hip_runtime.h>
#include <math.h>

#define B_  16
#define C_  256
#define N_  2048
#define CQ_ 64

typedef __attribute__((ext_vector_type(8))) short bf16x8;
typedef __attribute__((ext_vector_type(8))) unsigned short u16x8;
typedef __attribute__((ext_vector_type(16))) float f32x16;

__device__ __forceinline__ unsigned short f2bf(float f) {
  union { float f; unsigned u; } v; v.f = f;
  unsigned r = v.u + 0x7FFFu + ((v.u >> 16) & 1u);
  return (unsigned short)(r >> 16);
}

__device__ __forceinline__ void gload16(const void* g, void* l) {
  __builtin_amdgcn_global_load_lds(
      (const __attribute__((address_space(1))) void*)g,
      (__attribute__((address_space(3))) void*)l, 16, 0, 0);
}

__device__ __forceinline__ f32x16 zero16() {
  f32x16 z;
  #pragma unroll
  for (int i = 0; i < 16; ++i) z[i] = 0.f;
  return z;
}

// fragment read from a [rows][64] bf16 LDS tile with 16B-chunk XOR swizzle
__device__ __forceinline__ bf16x8 frag_ld(const unsigned short* base, int row, int kb, int hi) {
  const int byteoff = row * 128 + ((((kb << 1) + hi) ^ (row & 7)) << 4);
  return *(const bf16x8*)((const char*)base + byteoff);
}

// ---------------- Kernel 0a: pack weights -> bf16 swizzled Wall[384][256] ----
__global__ __launch_bounds__(256) void pack_kernel(
    const float* __restrict__ Wf, const float* __restrict__ bf,
    const float* __restrict__ Wg, const float* __restrict__ bg,
    const float* __restrict__ Wh, const float* __restrict__ bh,
    unsigned short* __restrict__ Wall, float* __restrict__ ball)
{
    const int t = threadIdx.x;
    const int o = blockIdx.x * 64 + (t >> 2);
    const int cq = (t & 3) * 64;
    const float* W; const float* bias; int r;
    if (o < 64)       { W = Wf; bias = bf; r = o; }
    else if (o < 128) { W = Wg; bias = bg; r = o - 64; }
    else              { W = Wh; bias = bh; r = o - 128; }
    for (int j = 0; j < 64; ++j) {
        const int c = cq + j;
        const int chunk = ((c >> 3) & 7) ^ (o & 7);
        Wall[(size_t)o * 256 + (c & ~63) + chunk * 8 + (c & 7)] = f2bf(W[(size_t)r * 256 + c]);
    }
    if ((t & 3) == 0) ball[o] = bias[r];
}

// ---------------- Kernel 0b: x [b][c][n] fp32 -> x_t [b][n][c] bf16 swz ------
__global__ __launch_bounds__(256) void xT_kernel(
    const float* __restrict__ x, unsigned short* __restrict__ x_t)
{
    const int b = blockIdx.z, g = blockIdx.y, n0 = blockIdx.x * 64;
    __shared__ float T[64][65];
    const int t = threadIdx.x;
    {
        const int c = t >> 4, n4 = (t & 15) * 4;
        #pragma unroll
        for (int p = 0; p < 4; ++p) {
            float4 v = *(const float4*)&x[((size_t)b * C_ + g * 64 + c + p * 16) * N_ + n0 + n4];
            T[c + p*16][n4+0] = v.x; T[c + p*16][n4+1] = v.y;
            T[c + p*16][n4+2] = v.z; T[c + p*16][n4+3] = v.w;
        }
    }
    __syncthreads();
    const int n = t >> 2, c16 = (t & 3) * 16;
    unsigned short* dst = x_t + ((size_t)b * N_ + n0 + n) * 256 + g * 64;
    #pragma unroll
    for (int k = 0; k < 2; ++k) {
        u16x8 v;
        #pragma unroll
        for (int j = 0; j < 8; ++j) v[j] = f2bf(T[c16 + k*8 + j][n]);
        const int ch = ((c16 >> 3) + k) ^ (n & 7);
        *(u16x8*)&dst[ch * 8] = v;
    }
}

// ---------------- Kernel 1: projections via MFMA (pipelined K) ---------------
__global__ __launch_bounds__(256) void projmm_kernel(
    const unsigned short* __restrict__ Wall, const float* __restrict__ ball,
    const unsigned short* __restrict__ x_t,
    unsigned short* __restrict__ f_t, unsigned short* __restrict__ g_t,
    unsigned short* __restrict__ h_sw)
{
    const int L = blockIdx.x;
    const int slot = L >> 3;
    const int b  = (L & 7) + (slot >= 48 ? 8 : 0);
    const int id2 = (slot >= 48) ? slot - 48 : slot;
    const int ot = id2 % 3, nt = id2 / 3;

    __shared__ __align__(16) unsigned short Sbuf[2][2][128 * 64]; // 64KB
    __shared__ float biasS[128];

    const int t = threadIdx.x, w = t >> 6, lane = t & 63, hi = lane >> 5, ln = lane & 31;
    const int oh = w & 1, nh = w >> 1;

    if (t < 128) biasS[t] = ball[ot * 128 + t];

    auto STAGE = [&](int k, int buf) {
        #pragma unroll
        for (int p = 0; p < 4; ++p) {
            const int q = p * 256 + t, r = q >> 3, cc = q & 7;
            gload16((const char*)Wall + ((size_t)(ot*128 + r) * 256 + k*64 + cc*8) * 2,
                    (char*)&Sbuf[buf][0][0] + q * 16);
            gload16((const char*)x_t + (((size_t)b * N_ + nt*128 + r) * 256 + k*64 + cc*8) * 2,
                    (char*)&Sbuf[buf][1][0] + q * 16);
        }
    };

    f32x16 a00 = zero16(), a01 = zero16(), a10 = zero16(), a11 = zero16();

    STAGE(0, 0);
    for (int k = 0; k < 4; ++k) {
        __syncthreads();   // drains stage k; prev compute reads done
        if (k < 3) STAGE(k + 1, (k + 1) & 1);
        const unsigned short* Wl = &Sbuf[k & 1][0][0];
        const unsigned short* Xl = &Sbuf[k & 1][1][0];
        #pragma unroll
        for (int kb = 0; kb < 4; ++kb) {
            bf16x8 w0 = frag_ld(Wl, oh*64 + ln,      kb, hi);
            bf16x8 w1 = frag_ld(Wl, oh*64 + 32 + ln, kb, hi);
            bf16x8 x0 = frag_ld(Xl, nh*64 + ln,      kb, hi);
            bf16x8 x1 = frag_ld(Xl, nh*64 + 32 + ln, kb, hi);
            a00 = __builtin_amdgcn_mfma_f32_32x32x16_bf16(w0, x0, a00, 0, 0, 0);
            a01 = __builtin_amdgcn_mfma_f32_32x32x16_bf16(w0, x1, a01, 0, 0, 0);
            a10 = __builtin_amdgcn_mfma_f32_32x32x16_bf16(w1, x0, a10, 0, 0, 0);
            a11 = __builtin_amdgcn_mfma_f32_32x32x16_bf16(w1, x1, a11, 0, 0, 0);
        }
    }

    if (ot == 0) {
        unsigned short* y = (oh == 0) ? f_t : g_t;
        #pragma unroll
        for (int j = 0; j < 2; ++j) {
            const int n = nh*64 + j*32 + ln;
            #pragma unroll
            for (int i = 0; i < 2; ++i) {
                const f32x16& a = (i == 0) ? (j == 0 ? a00 : a01)
                                           : (j == 0 ? a10 : a11);
                #pragma unroll
                for (int q = 0; q < 4; ++q) {
                    const int c0 = i*32 + q*8 + 4*hi;
                    ushort4 u;
                    u.x = f2bf(fmaxf(a[q*4+0] + biasS[oh*64 + c0 + 0], 0.f));
                    u.y = f2bf(fmaxf(a[q*4+1] + biasS[oh*64 + c0 + 1], 0.f));
                    u.z = f2bf(fmaxf(a[q*4+2] + biasS[oh*64 + c0 + 2], 0.f));
                    u.w = f2bf(fmaxf(a[q*4+3] + biasS[oh*64 + c0 + 3], 0.f));
                    *(ushort4*)&y[((size_t)b * N_ + nt*128 + n) * CQ_ +
                                  ((((c0 >> 3) ^ (n & 7)) << 3) + 4*hi)] = u;
                }
            }
        }
    } else {
        __syncthreads();
        unsigned short* Ht = &Sbuf[0][0][0];   // 128 x 128 bf16 = 32KB
        #pragma unroll
        for (int j = 0; j < 2; ++j) {
            const int n_lo = nh*64 + j*32 + ln;
            const int chunk = n_lo >> 3;
            #pragma unroll
            for (int i = 0; i < 2; ++i) {
                const f32x16& a = (i == 0) ? (j == 0 ? a00 : a01)
                                           : (j == 0 ? a10 : a11);
                #pragma unroll
                for (int r = 0; r < 16; ++r) {
                    const int o_lo = oh*64 + i*32 + (r & 3) + ((r >> 2) << 3) + 4*hi;
                    const int chs = (chunk & 8) | ((chunk ^ o_lo) & 7);
                    Ht[o_lo * 128 + chs * 8 + (n_lo & 7)] =
                        f2bf(fmaxf(a[r] + biasS[o_lo], 0.f));
                }
            }
        }
        __syncthreads();
        const int o_l = t >> 1, half = t & 1;
        const int c = (ot - 1) * 128 + o_l;
        unsigned short* dst = h_sw + ((size_t)b * C_ + c) * N_ + (nt*2 + half) * 64;
        const unsigned short* src = Ht + o_l * 128 + half * 64;
        #pragma unroll
        for (int c8 = 0; c8 < 8; ++c8)
            *(u16x8*)&dst[c8 * 8] = *(const u16x8*)&src[c8 * 8];
    }
}

// ---------------- Kernel 2: row stats via MFMA (pipelined F staging) ---------
__global__ __launch_bounds__(256) void stats_kernel(
    const unsigned short* __restrict__ f_t, const unsigned short* __restrict__ g_t,
    float* __restrict__ Mw, float* __restrict__ rZw)
{
    const int L = blockIdx.x;
    const int slot = L >> 3;
    const int b  = (L & 7) + (slot >= 32 ? 8 : 0);
    const int nb = ((slot >= 32) ? slot - 32 : slot) * 64;

    __shared__ __align__(16) unsigned short G_lds[64*64];
    __shared__ __align__(16) unsigned short F_lds[2][64*64];
    __shared__ float pM[2][64];
    __shared__ float pZ[2][64];

    const int t = threadIdx.x;
    const int w = t >> 6, lane = t & 63, hi = lane >> 5, ln = lane & 31;
    const int mb = w >> 1, nb2 = w & 1;

    auto STAGE_F = [&](int s, int buf) {
        const char* fsrc = (const char*)(f_t + ((size_t)b * N_ + s * 64) * CQ_);
        #pragma unroll
        for (int p = 0; p < 2; ++p) {
            const int off = (w * 2 + p) * 1024;
            gload16(fsrc + off + lane * 16, (char*)&F_lds[buf][0] + off);
        }
    };

    {
        const char* gsrc = (const char*)(g_t + ((size_t)b * N_ + nb) * CQ_);
        #pragma unroll
        for (int p = 0; p < 2; ++p) {
            const int off = (w * 2 + p) * 1024;
            gload16(gsrc + off + lane * 16, (char*)G_lds + off);
        }
        STAGE_F(0, 0);
    }

    float runM = -1e30f, runZ = 0.f;
    constexpr int NS = N_ / 64;

    for (int s = 0; s < NS; ++s) {
        __syncthreads();    // drains stage s (and G on s=0); prev reads done
        if (s + 1 < NS) STAGE_F(s + 1, (s + 1) & 1);

        f32x16 sacc = zero16();
        #pragma unroll
        for (int kb = 0; kb < 4; ++kb) {
            bf16x8 a  = frag_ld(&F_lds[s & 1][0], mb * 32 + ln, kb, hi);
            bf16x8 g8 = frag_ld(G_lds, nb2 * 32 + ln, kb, hi);
            sacc = __builtin_amdgcn_mfma_f32_32x32x16_bf16(a, g8, sacc, 0, 0, 0);
        }

        float lm = sacc[0];
        #pragma unroll
        for (int r = 1; r < 16; ++r) lm = fmaxf(lm, sacc[r]);
        const float nm = fmaxf(runM, lm);
        float ssum = 0.f;
        #pragma unroll
        for (int r = 0; r < 16; ++r) ssum += __expf(sacc[r] - nm);
        runZ = runZ * __expf(runM - nm) + ssum;
        runM = nm;
    }

    {
        const float oM = __shfl_xor(runM, 32);
        const float oZ = __shfl_xor(runZ, 32);
        const float Mf = fmaxf(runM, oM);
        const float Zf = runZ * __expf(runM - Mf) + oZ * __expf(oM - Mf);
        if (lane < 32) { pM[mb][nb2 * 32 + lane] = Mf; pZ[mb][nb2 * 32 + lane] = Zf; }
    }
    __syncthreads();
    if (t < 64) {
        const float m0 = pM[0][t], m1 = pM[1][t];
        const float M  = fmaxf(m0, m1);
        const float Z  = pZ[0][t] * __expf(m0 - M) + pZ[1][t] * __expf(m1 - M);
        Mw[(size_t)b * N_ + nb + t]  = M;
        rZw[(size_t)b * N_ + nb + t] = 1.0f / Z;
    }
}

// ---------------- Kernel 3: fused output, single-barrier pipeline ------------
// Per iter tt: barrier -> issue H(tt+1),G(tt+2) -> S-MFMA(tt+1) -> PV(tt) -> exp->P
__global__ __launch_bounds__(512) void out_kernel(
    const float* __restrict__ x,
    const unsigned short* __restrict__ f_t, const unsigned short* __restrict__ g_t,
    const unsigned short* __restrict__ h_sw,
    const float* __restrict__ Mw, const float* __restrict__ rZw,
    const float* __restrict__ gamma_p, float* __restrict__ out)
{
    const int L = blockIdx.x;
    const int slot = L >> 3;
    const int b = (L & 7) + (slot >= 16 ? 8 : 0);
    const int mbase = ((slot >= 16) ? slot - 16 : slot) * 128;

    __shared__ __align__(16) unsigned short F_lds[128*64];      // 16 KB
    __shared__ __align__(16) unsigned short G_lds[2][64*64];    // 16 KB
    __shared__ __align__(16) unsigned short H_lds[2][256*64];   // 64 KB
    __shared__ __align__(16) unsigned short P_lds[2][128*64];   // 32 KB
    __shared__ __align__(16) float M_lds[N_];                   // 8 KB
    __shared__ __align__(16) float Z_lds[N_];                   // 8 KB

    const int t = threadIdx.x;
    const int w = t >> 6, lane = t & 63, hi = lane >> 5, ln = lane & 31;
    const int amb = w & 3, anb = w >> 2;
    const int cb  = w & 3, mbw = w >> 2;
    const int nloc = anb * 32 + ln;

    auto STAGE_G = [&](int tt, int buf) {
        const char* gsrc = (const char*)(g_t + ((size_t)b * N_ + tt * 64) * CQ_);
        gload16(gsrc + w * 1024 + lane * 16, (char*)&G_lds[buf][0] + w * 1024);
    };
    auto STAGE_H = [&](int tt, int buf) {
        const char* hsrc = (const char*)h_sw + ((size_t)b * C_) * (N_ * 2) + (size_t)tt * 128;
        #pragma unroll
        for (int p = 0; p < 4; ++p) {
            const int c0 = w * 32 + p * 8;
            gload16(hsrc + (size_t)(c0 + (lane >> 3)) * (N_ * 2) + (lane & 7) * 16,
                    (char*)&H_lds[buf][0] + c0 * 128);
        }
    };

    // prologue staging
    {
        const char* fsrc = (const char*)(f_t + ((size_t)b * N_ + mbase) * CQ_);
        gload16(fsrc + w * 2048 + lane * 16, (char*)F_lds + w * 2048);
        gload16(fsrc + w * 2048 + 1024 + lane * 16, (char*)F_lds + w * 2048 + 1024);
        const char* msrc = (const char*)(Mw + (size_t)b * N_);
        gload16(msrc + w * 1024 + lane * 16, (char*)M_lds + w * 1024);
        const char* zsrc = (const char*)(rZw + (size_t)b * N_);
        gload16(zsrc + w * 1024 + lane * 16, (char*)Z_lds + w * 1024);
        STAGE_G(0, 0);
        STAGE_G(1, 1);
        STAGE_H(0, 0);
    }
    __syncthreads();

    // S(0) -> P[0]
    {
        f32x16 sacc = zero16();
        #pragma unroll
        for (int kb = 0; kb < 4; ++kb) {
            bf16x8 a  = frag_ld(F_lds, amb * 32 + ln, kb, hi);
            bf16x8 g8 = frag_ld(&G_lds[0][0], anb * 32 + ln, kb, hi);
            sacc = __builtin_amdgcn_mfma_f32_32x32x16_bf16(a, g8, sacc, 0, 0, 0);
        }
        const float Mv  = M_lds[nloc];
        const float rZv = Z_lds[nloc];
        #pragma unroll
        for (int r = 0; r < 16; ++r) {
            const int m = amb * 32 + (r & 3) + ((r >> 2) << 3) + (hi << 2);
            const float p = __expf(sacc[r] - Mv) * rZv;
            *(unsigned short*)((char*)&P_lds[0][0] + m * 128 +
                ((((nloc >> 3) ^ (m & 7)) << 4) | ((nloc & 7) << 1))) = f2bf(p);
        }
    }

    f32x16 acc00 = zero16(), acc01 = zero16(), acc10 = zero16(), acc11 = zero16();
    constexpr int NT = N_ / 64;

    for (int tt = 0; tt < NT; ++tt) {
        const int cur = tt & 1;
        __syncthreads();   // P[cur] visible; stage(tt) drained; prev-buf reads done

        if (tt + 1 < NT) {
            STAGE_H(tt + 1, cur ^ 1);
            if (tt + 2 < NT) STAGE_G(tt + 2, cur);
        }

        f32x16 sacc = zero16();
        if (tt + 1 < NT) {
            #pragma unroll
            for (int kb = 0; kb < 4; ++kb) {
                bf16x8 a  = frag_ld(F_lds, amb * 32 + ln, kb, hi);
                bf16x8 g8 = frag_ld(&G_lds[cur ^ 1][0], anb * 32 + ln, kb, hi);
                sacc = __builtin_amdgcn_mfma_f32_32x32x16_bf16(a, g8, sacc, 0, 0, 0);
            }
        }

        __builtin_amdgcn_s_setprio(1);
        #pragma unroll
        for (int kb = 0; kb < 4; ++kb) {
            bf16x8 ha0 = frag_ld(&H_lds[cur][0], cb * 64 + ln,      kb, hi);
            bf16x8 ha1 = frag_ld(&H_lds[cur][0], cb * 64 + 32 + ln, kb, hi);
            bf16x8 pb0 = frag_ld(&P_lds[cur][0], mbw * 64 + ln,      kb, hi);
            bf16x8 pb1 = frag_ld(&P_lds[cur][0], mbw * 64 + 32 + ln, kb, hi);
            acc00 = __builtin_amdgcn_mfma_f32_32x32x16_bf16(ha0, pb0, acc00, 0, 0, 0);
            acc01 = __builtin_amdgcn_mfma_f32_32x32x16_bf16(ha0, pb1, acc01, 0, 0, 0);
            acc10 = __builtin_amdgcn_mfma_f32_32x32x16_bf16(ha1, pb0, acc10, 0, 0, 0);
            acc11 = __builtin_amdgcn_mfma_f32_32x32x16_bf16(ha1, pb1, acc11, 0, 0, 0);
        }
        __builtin_amdgcn_s_setprio(0);

        if (tt + 1 < NT) {
            const float Mv  = M_lds[(tt + 1) * 64 + nloc];
            const float rZv = Z_lds[(tt + 1) * 64 + nloc];
            #pragma unroll
            for (int r = 0; r < 16; ++r) {
                const int m = amb * 32 + (r & 3) + ((r >> 2) << 3) + (hi << 2);
                const float p = __expf(sacc[r] - Mv) * rZv;
                *(unsigned short*)((char*)&P_lds[cur ^ 1][0] + m * 128 +
                    ((((nloc >> 3) ^ (m & 7)) << 4) | ((nloc & 7) << 1))) = f2bf(p);
            }
        }
    }

    const float gamma = gamma_p[0];
    #pragma unroll
    for (int ci = 0; ci < 2; ++ci) {
        #pragma unroll
        for (int mi = 0; mi < 2; ++mi) {
            const f32x16& a = (ci == 0) ? (mi == 0 ? acc00 : acc01)
                                        : (mi == 0 ? acc10 : acc11);
            #pragma unroll
            for (int r = 0; r < 16; ++r) {
                const int c = cb * 64 + ci * 32 + (r & 3) + ((r >> 2) << 3) + (hi << 2);
                const int m = mbase + mbw * 64 + mi * 32 + ln;
                const size_t idx = ((size_t)b * C_ + c) * N_ + m;
                out[idx] = fmaf(gamma, a[r], x[idx]);
            }
        }
    }
}

extern "C" void kernel_launch(void* const* d_in, const int* in_sizes, int n_in,
                              void* d_out, int out_size, void* d_ws, size_t ws_size,
                              hipStream_t stream)
{
    (void)in_sizes; (void)n_in; (void)out_size; (void)ws_size;
    const float* x     = (const float*)d_in[0];
    const float* Wf    = (const float*)d_in[1];
    const float* bf    = (const float*)d_in[2];
    const float* Wg    = (const float*)d_in[3];
    const float* bg    = (const float*)d_in[4];
    const float* Wh    = (const float*)d_in[5];
    const float* bh    = (const float*)d_in[6];
    const float* gamma = (const float*)d_in[7];
    float* out = (float*)d_out;

    unsigned short* f_t  = (unsigned short*)d_ws;
    unsigned short* g_t  = f_t + (size_t)B_ * N_ * CQ_;
    unsigned short* h_sw = g_t + (size_t)B_ * N_ * CQ_;
    float* M_ws  = (float*)(h_sw + (size_t)B_ * C_ * N_);
    float* rZ_ws = M_ws + (size_t)B_ * N_;
    unsigned short* x_t  = (unsigned short*)(rZ_ws + (size_t)B_ * N_);
    unsigned short* Wall = x_t + (size_t)B_ * N_ * C_;
    float* ball  = (float*)(Wall + (size_t)384 * 256);

    pack_kernel<<<dim3(6), 256, 0, stream>>>(Wf, bf, Wg, bg, Wh, bh, Wall, ball);
    xT_kernel<<<dim3(N_/64, C_/64, B_), 256, 0, stream>>>(x, x_t);
    projmm_kernel<<<dim3(768), 256, 0, stream>>>(Wall, ball, x_t, f_t, g_t, h_sw);
    stats_kernel<<<dim3(512), 256, 0, stream>>>(f_t, g_t, M_ws, rZ_ws);
    out_kernel<<<dim3(256), 512, 0, stream>>>(x, f_t, g_t, h_sw, M_ws, rZ_ws, gamma, out);
}